// Round 12
// baseline (59.163 us; speedup 1.0000x reference)
//
#include <hip/hip_runtime.h>
#include <math.h>

// LazyEqProp closed form (verified rounds 1-11):
//   E  = x @ We^T + be
//   m0 = mean|E|  > eps ;  H0 = m0 * 0.5*tanh(E  @ W0^T + b0)
//   m1 = mean|H0| > eps ;  H1 = m1 * 0.5*tanh(H0 @ W1^T + b1)
//   m2 = mean|H1| > eps ;  H2 = m2 * 0.5*tanh(H1 @ W2^T + b2)
//   out = H2 @ Wh^T + bh
//
// Round 12: r6 skeleton + k-split waves. 8 waves = 2 k-groups x 4 waves of
// 64x32 tiles: 6 ds_read_b128 per 8 MFMA (was 8 per 8) -> per-step LDS reads
// 64->48 KB. Half-K partials merged via one 32 KB LDS reduction after the
// loop (reuses buf0; conflict-free lane-major layout). Everything else
// byte-identical to round 6: BK=64, triple buffer 72 KB, counted vmcnt(3),
// depth-2 prefetch, setprio, swizzled-f16 global layout, global_load_lds
// width-16, fused mask epilogue + atomicAdd row sums, XCD-aware block map.

using half_t = _Float16;
typedef _Float16 f16x4 __attribute__((ext_vector_type(4)));
typedef _Float16 f16x8 __attribute__((ext_vector_type(8)));
typedef float    f32x4 __attribute__((ext_vector_type(4)));

constexpr int KDIM = 1024;
constexpr int ROWB = KDIM * 2;  // bytes per swizzled f16 row
constexpr float EPS_GATE = 0.01f;

__device__ __forceinline__ float tanh_fast(float z) {
    return 1.0f - 2.0f / (__expf(2.0f * z) + 1.0f);  // safe at +-inf
}

__device__ __forceinline__ void gload16(const void* g, void* l) {
    __builtin_amdgcn_global_load_lds(
        (const __attribute__((address_space(1))) void*)g,
        (__attribute__((address_space(3))) void*)l, 16, 0, 0);
}

// ---- fp32 -> swizzled fp16 (row r, byte p holds element (p ^ ((r&7)<<4))/2)
//      + zero the 3 row-sum accumulators (blocks 0..5)
__global__ __launch_bounds__(256)
void convert_all(const float* __restrict__ x,  const float* __restrict__ We,
                 const float* __restrict__ W,  const float* __restrict__ Wh,
                 half_t* __restrict__ x16, half_t* __restrict__ We16,
                 half_t* __restrict__ W16, half_t* __restrict__ Wh16,
                 float* __restrict__ msum) {
    const int bid = blockIdx.x;
    const int t = threadIdx.x;
    if (bid < 6) ((f32x4*)msum)[bid * 256 + t] = f32x4{0.f, 0.f, 0.f, 0.f};
    const float* src; half_t* dst; int row;
    if (bid < 2048)      { src = x;  dst = x16;  row = bid; }
    else if (bid < 3072) { src = We; dst = We16; row = bid - 2048; }
    else if (bid < 6144) { src = W;  dst = W16;  row = bid - 3072; }
    else                 { src = Wh; dst = Wh16; row = bid - 6144; }
    const f32x4 v = *(const f32x4*)(src + (size_t)row * KDIM + 4 * t);
    f16x4 h;
    h[0] = (half_t)v[0]; h[1] = (half_t)v[1]; h[2] = (half_t)v[2]; h[3] = (half_t)v[3];
    const int p = (8 * t) ^ ((row & 7) << 4);
    *(f16x4*)((char*)dst + (size_t)row * ROWB + p) = h;
}

// ---- NT gemm: O[m,n] = epi( sum_k P[m,k]*Q[n,k] + bias[n] )
// P,Q swizzled f16. Tile 128m x 64n x 64k; 8 waves = 2 k-groups x (2m x 2n),
// wave tile 64x32. Triple-buffered LDS, counted vmcnt(3), setprio.
// EPI: 0 = bias -> swz f16; 1 = mask(msum_in)*0.5*tanh(.+bias) -> swz f16;
//      2 = bias -> f32.  EMIT: atomicAdd per-row |out| partials.
template <int EPI, bool EMIT>
__global__ __launch_bounds__(512)
void gemm8w(const half_t* __restrict__ P, const half_t* __restrict__ Q,
            const float* __restrict__ bias, const float* __restrict__ msum_in,
            float* __restrict__ msum_out, void* __restrict__ Out, int Nout) {
    // 3 buffers x (P 16 KB | Q 8 KB) = 72 KB; reduction reuses first 32 KB
    __shared__ alignas(16) char smem[3 * 24576];

    const int tid = threadIdx.x;
    const int bid = blockIdx.x;
    // XCD-aware: xcd = bid&7 owns m-tiles {2x,2x+1} across all n-tiles.
    const int m0 = ((bid & 7) * 2 + ((bid >> 3) & 1)) * 128;
    const int n0 = (bid >> 4) * 64;

    // staging: 3 x 16B granules/thread, LDS dest = uniform base + tid*16
    const char* gP0 = (const char*)P + (size_t)(m0 + (tid >> 3)) * ROWB + (tid & 7) * 16;
    const char* gP1 = gP0 + (size_t)64 * ROWB;
    const char* gQ  = (const char*)Q + (size_t)(n0 + (tid >> 3)) * ROWB + (tid & 7) * 16;
    const int ldsT = tid * 16;

    const int lane = tid & 63;
    const int w = tid >> 6;
    const int g = w >> 2;            // k-group: 0 -> k[0,32), 1 -> k[32,64)
    const int sub = w & 3;           // 2m x 2n within the group
    const int wm = (sub & 1) * 64;
    const int wn = (sub >> 1) * 32;
    const int l15 = lane & 15, l4 = lane >> 4;
    const int off0 = (l4 * 16) ^ ((lane & 7) << 4);
    const int ko = g ? (off0 ^ 64) : off0;   // this wave's k-slice offset

    f32x4 acc[2][4] = {};  // [n-frag i][m-frag j]

    auto stage = [&](int s) {
        const int go = s * 128;
        char* base = smem + (s % 3) * 24576;
        gload16(gP0 + go, base + ldsT);
        gload16(gP1 + go, base + 8192 + ldsT);
        gload16(gQ + go, base + 16384 + ldsT);
    };

    stage(0);
    stage(1);

    for (int s = 0; s < 16; ++s) {
        // own DMAs for tile s done; tile s+1's 3 stay in flight.
        if (s == 15) asm volatile("s_waitcnt vmcnt(0)" ::: "memory");
        else         asm volatile("s_waitcnt vmcnt(3)" ::: "memory");
        __builtin_amdgcn_s_barrier();   // all waves' tile-s DMAs landed
        asm volatile("" ::: "memory");
        if (s < 14) stage(s + 2);       // overwrites buf((s-1)%3): reads done
        const char* PtB = smem + (s % 3) * 24576;
        const char* QtB = PtB + 16384;
        __builtin_amdgcn_s_setprio(1);
        f16x8 qa[2], pb[4];
#pragma unroll
        for (int i = 0; i < 2; ++i)
            qa[i] = *(const f16x8*)(QtB + (wn + i * 16 + l15) * 128 + ko);
#pragma unroll
        for (int j = 0; j < 4; ++j)
            pb[j] = *(const f16x8*)(PtB + (wm + j * 16 + l15) * 128 + ko);
#pragma unroll
        for (int i = 0; i < 2; ++i)
#pragma unroll
            for (int j = 0; j < 4; ++j)
                acc[i][j] = __builtin_amdgcn_mfma_f32_16x16x32_f16(qa[i], pb[j], acc[i][j], 0, 0, 0);
        __builtin_amdgcn_s_setprio(0);
    }

    // ---- merge the two k-group partials via LDS (32 KB, reuses buf0)
    __syncthreads();  // K-loop LDS reads complete before overwrite
    if (g == 1) {
#pragma unroll
        for (int i = 0; i < 2; ++i)
#pragma unroll
            for (int j = 0; j < 4; ++j)
                *(f32x4*)(smem + sub * 8192 + (j * 2 + i) * 1024 + lane * 16) = acc[i][j];
    }
    __syncthreads();
    if (g == 1) return;  // group 1 done (no barriers below)
#pragma unroll
    for (int i = 0; i < 2; ++i)
#pragma unroll
        for (int j = 0; j < 4; ++j)
            acc[i][j] += *(const f32x4*)(smem + sub * 8192 + (j * 2 + i) * 1024 + lane * 16);

    // ---- epilogue (group 0): m = m0+wm+j*16+l15, n = n0+wn+i*16+l4*4+e
#pragma unroll
    for (int j = 0; j < 4; ++j) {
        const int m = m0 + wm + j * 16 + l15;
        float msk = 1.0f;
        if (EPI == 1) msk = (msum_in[m] * (1.0f / 1024.0f) > EPS_GATE) ? 1.0f : 0.0f;
        float rsum = 0.0f;
#pragma unroll
        for (int i = 0; i < 2; ++i) {
            const int n = n0 + wn + i * 16 + l4 * 4;
            const f32x4 bz = *(const f32x4*)(bias + n);
            float v[4];
#pragma unroll
            for (int e = 0; e < 4; ++e) {
                v[e] = acc[i][j][e] + bz[e];
                if (EPI == 1) v[e] = msk * (0.5f * tanh_fast(v[e]));
                if (EMIT) rsum += fabsf(v[e]);
            }
            if (EPI == 2) {
                f32x4 o; o[0] = v[0]; o[1] = v[1]; o[2] = v[2]; o[3] = v[3];
                *(f32x4*)((float*)Out + (size_t)m * Nout + n) = o;
            } else {
                f16x4 hv;
                hv[0] = (half_t)v[0]; hv[1] = (half_t)v[1];
                hv[2] = (half_t)v[2]; hv[3] = (half_t)v[3];
                const int p = (n * 2) ^ ((m & 7) << 4);
                *(f16x4*)((char*)Out + (size_t)m * ROWB + p) = hv;
            }
        }
        if (EMIT) {  // reduce over the 4 l4-lanes sharing this row, one atomic
            rsum += __shfl_xor(rsum, 16, 64);
            rsum += __shfl_xor(rsum, 32, 64);
            if (l4 == 0) atomicAdd(msum_out + m, rsum);
        }
    }
}

extern "C" void kernel_launch(void* const* d_in, const int* in_sizes, int n_in,
                              void* d_out, int out_size, void* d_ws, size_t ws_size,
                              hipStream_t stream) {
    const float* x  = (const float*)d_in[0];  // [2048,1024]
    const float* We = (const float*)d_in[1];  // [1024,1024]
    const float* be = (const float*)d_in[2];  // [1024]
    const float* W  = (const float*)d_in[3];  // [3,1024,1024]
    const float* b  = (const float*)d_in[4];  // [3,1024]
    const float* Wh = (const float*)d_in[5];  // [512,1024]
    const float* bh = (const float*)d_in[6];  // [512]

    const int B = 2048, H = 1024, O = 512;

    half_t* s0   = (half_t*)d_ws;                   // x16 / H0 / H2
    half_t* s1   = s0 + (size_t)B * H;              // E / H1
    half_t* We16 = s1 + (size_t)B * H;
    half_t* W16  = We16 + (size_t)H * H;
    half_t* Wh16 = W16 + (size_t)3 * H * H;
    float*  msum = (float*)(Wh16 + (size_t)O * H);  // 3 x 2048 f32
    float*  out  = (float*)d_out;

    convert_all<<<6656, 256, 0, stream>>>(x, We, W, Wh, s0, We16, W16, Wh16, msum);

    // E = x @ We^T + be; emit |E| row sums -> msum0
    gemm8w<0, true ><<<256, 512, 0, stream>>>(s0, We16, be, nullptr, msum, s1, H);
    // H0 = m0 * 0.5*tanh(E @ W0^T + b0); emit -> msum1
    gemm8w<1, true ><<<256, 512, 0, stream>>>(s1, W16, b, msum, msum + 2048, s0, H);
    // H1; emit -> msum2
    gemm8w<1, true ><<<256, 512, 0, stream>>>(s0, W16 + (size_t)H * H, b + H,
                                              msum + 2048, msum + 4096, s1, H);
    // H2 (no emit)
    gemm8w<1, false><<<256, 512, 0, stream>>>(s1, W16 + (size_t)2 * H * H, b + 2 * H,
                                              msum + 4096, nullptr, s0, H);
    // head -> f32 out
    gemm8w<2, false><<<128, 512, 0, stream>>>(s0, Wh16, bh, nullptr, nullptr, out, O);
}

// Round 13
// 53.897 us; speedup vs baseline: 1.0977x; 1.0977x over previous
//
#include <hip/hip_runtime.h>
#include <math.h>

// LazyEqProp closed form (verified rounds 1-12):
//   E  = x @ We^T + be
//   m0 = mean|E|  > eps ;  H0 = m0 * 0.5*tanh(E  @ W0^T + b0)
//   m1 = mean|H0| > eps ;  H1 = m1 * 0.5*tanh(H0 @ W1^T + b1)
//   m2 = mean|H1| > eps ;  H2 = m2 * 0.5*tanh(H1 @ W2^T + b2)
//   out = H2 @ Wh^T + bh
//
// Round 13: round-6 structure verbatim (best: 54.85us) with ONE change:
// the head gemm (2048x512) used 128x64 tiles = 128 blocks = HALF the CUs,
// costing a full big-gemm time. Switch head to round-11's proven 64x64-tile
// 4-wave gemm2b (grid 256: all CUs, half per-block work). Everything else
// byte-identical to round 6.

using half_t = _Float16;
typedef _Float16 f16x4 __attribute__((ext_vector_type(4)));
typedef _Float16 f16x8 __attribute__((ext_vector_type(8)));
typedef float    f32x4 __attribute__((ext_vector_type(4)));

constexpr int KDIM = 1024;
constexpr int ROWB = KDIM * 2;  // bytes per swizzled f16 row
constexpr float EPS_GATE = 0.01f;

__device__ __forceinline__ float tanh_fast(float z) {
    return 1.0f - 2.0f / (__expf(2.0f * z) + 1.0f);  // safe at +-inf
}

__device__ __forceinline__ void gload16(const void* g, void* l) {
    __builtin_amdgcn_global_load_lds(
        (const __attribute__((address_space(1))) void*)g,
        (__attribute__((address_space(3))) void*)l, 16, 0, 0);
}

// ---- fp32 -> swizzled fp16 (row r, byte p holds element (p ^ ((r&7)<<4))/2)
//      + zero the 3 row-sum accumulators (blocks 0..5)
__global__ __launch_bounds__(256)
void convert_all(const float* __restrict__ x,  const float* __restrict__ We,
                 const float* __restrict__ W,  const float* __restrict__ Wh,
                 half_t* __restrict__ x16, half_t* __restrict__ We16,
                 half_t* __restrict__ W16, half_t* __restrict__ Wh16,
                 float* __restrict__ msum) {
    const int bid = blockIdx.x;
    const int t = threadIdx.x;
    if (bid < 6) ((f32x4*)msum)[bid * 256 + t] = f32x4{0.f, 0.f, 0.f, 0.f};
    const float* src; half_t* dst; int row;
    if (bid < 2048)      { src = x;  dst = x16;  row = bid; }
    else if (bid < 3072) { src = We; dst = We16; row = bid - 2048; }
    else if (bid < 6144) { src = W;  dst = W16;  row = bid - 3072; }
    else                 { src = Wh; dst = Wh16; row = bid - 6144; }
    const f32x4 v = *(const f32x4*)(src + (size_t)row * KDIM + 4 * t);
    f16x4 h;
    h[0] = (half_t)v[0]; h[1] = (half_t)v[1]; h[2] = (half_t)v[2]; h[3] = (half_t)v[3];
    const int p = (8 * t) ^ ((row & 7) << 4);
    *(f16x4*)((char*)dst + (size_t)row * ROWB + p) = h;
}

// ---- NT gemm (round-6): tile 128m x 64n x 64k; 8 waves (4m x 2n), wave tile
// 32x32; triple-buffered LDS (3 x 24 KB), counted vmcnt(3), setprio.
// EPI: 0 = bias -> swz f16; 1 = mask(msum_in)*0.5*tanh(.+bias) -> swz f16;
//      2 = bias -> f32.  EMIT: atomicAdd per-row |out| partials.
template <int EPI, bool EMIT>
__global__ __launch_bounds__(512)
void gemm8w(const half_t* __restrict__ P, const half_t* __restrict__ Q,
            const float* __restrict__ bias, const float* __restrict__ msum_in,
            float* __restrict__ msum_out, void* __restrict__ Out, int Nout) {
    __shared__ alignas(16) char smem[3 * 24576];

    const int tid = threadIdx.x;
    const int bid = blockIdx.x;
    // XCD-aware: xcd = bid&7 owns m-tiles {2x,2x+1} across all n-tiles.
    const int m0 = ((bid & 7) * 2 + ((bid >> 3) & 1)) * 128;
    const int n0 = (bid >> 4) * 64;

    const char* gP0 = (const char*)P + (size_t)(m0 + (tid >> 3)) * ROWB + (tid & 7) * 16;
    const char* gP1 = gP0 + (size_t)64 * ROWB;
    const char* gQ  = (const char*)Q + (size_t)(n0 + (tid >> 3)) * ROWB + (tid & 7) * 16;
    const int ldsT = tid * 16;

    const int lane = tid & 63;
    const int w = tid >> 6;
    const int wm = (w & 3) * 32;
    const int wn = (w >> 2) * 32;
    const int l15 = lane & 15, l4 = lane >> 4;
    const int off0 = (l4 * 16) ^ ((lane & 7) << 4);
    const int off1 = off0 ^ 64;

    f32x4 acc[2][2] = {};  // [n-frag][m-frag]

    auto stage = [&](int s) {
        const int go = s * 128;
        char* base = smem + (s % 3) * 24576;
        gload16(gP0 + go, base + ldsT);
        gload16(gP1 + go, base + 8192 + ldsT);
        gload16(gQ + go, base + 16384 + ldsT);
    };

    stage(0);
    stage(1);

    for (int s = 0; s < 16; ++s) {
        if (s == 15) asm volatile("s_waitcnt vmcnt(0)" ::: "memory");
        else         asm volatile("s_waitcnt vmcnt(3)" ::: "memory");
        __builtin_amdgcn_s_barrier();   // all waves' tile-s DMAs landed
        asm volatile("" ::: "memory");
        if (s < 14) stage(s + 2);       // overwrites buf((s-1)%3): reads done
        const char* PtB = smem + (s % 3) * 24576;
        const char* QtB = PtB + 16384;
        __builtin_amdgcn_s_setprio(1);
#pragma unroll
        for (int h = 0; h < 2; ++h) {
            const int ko = h ? off1 : off0;
            f16x8 qa[2], pb[2];
#pragma unroll
            for (int i = 0; i < 2; ++i)
                qa[i] = *(const f16x8*)(QtB + (wn + i * 16 + l15) * 128 + ko);
#pragma unroll
            for (int j = 0; j < 2; ++j)
                pb[j] = *(const f16x8*)(PtB + (wm + j * 16 + l15) * 128 + ko);
#pragma unroll
            for (int i = 0; i < 2; ++i)
#pragma unroll
                for (int j = 0; j < 2; ++j)
                    acc[i][j] = __builtin_amdgcn_mfma_f32_16x16x32_f16(qa[i], pb[j], acc[i][j], 0, 0, 0);
        }
        __builtin_amdgcn_s_setprio(0);
    }

    // ---- epilogue: lane holds m = m0+wm+j*16+l15, n = n0+wn+i*16+l4*4+e
#pragma unroll
    for (int j = 0; j < 2; ++j) {
        const int m = m0 + wm + j * 16 + l15;
        float msk = 1.0f;
        if (EPI == 1) msk = (msum_in[m] * (1.0f / 1024.0f) > EPS_GATE) ? 1.0f : 0.0f;
        float rsum = 0.0f;
#pragma unroll
        for (int i = 0; i < 2; ++i) {
            const int n = n0 + wn + i * 16 + l4 * 4;
            const f32x4 bz = *(const f32x4*)(bias + n);
            float v[4];
#pragma unroll
            for (int e = 0; e < 4; ++e) {
                v[e] = acc[i][j][e] + bz[e];
                if (EPI == 1) v[e] = msk * (0.5f * tanh_fast(v[e]));
                if (EMIT) rsum += fabsf(v[e]);
            }
            if (EPI == 2) {
                f32x4 o; o[0] = v[0]; o[1] = v[1]; o[2] = v[2]; o[3] = v[3];
                *(f32x4*)((float*)Out + (size_t)m * Nout + n) = o;
            } else {
                f16x4 hv;
                hv[0] = (half_t)v[0]; hv[1] = (half_t)v[1];
                hv[2] = (half_t)v[2]; hv[3] = (half_t)v[3];
                const int p = (n * 2) ^ ((m & 7) << 4);
                *(f16x4*)((char*)Out + (size_t)m * ROWB + p) = hv;
            }
        }
        if (EMIT) {  // reduce over the 4 l4-lanes sharing this row, one atomic
            rsum += __shfl_xor(rsum, 16, 64);
            rsum += __shfl_xor(rsum, 32, 64);
            if (l4 == 0) atomicAdd(msum_out + m, rsum);
        }
    }
}

// ---- NT gemm (round-11): tile 64m x 64n x 64k; 4 waves (2m x 2n), 256 thr,
// 48 KB LDS. Used for the HEAD only (grid 256 = all CUs, half per-block work).
template <int EPI, bool EMIT>
__global__ __launch_bounds__(256)
void gemm2b(const half_t* __restrict__ P, const half_t* __restrict__ Q,
            const float* __restrict__ bias, const float* __restrict__ msum_in,
            float* __restrict__ msum_out, void* __restrict__ Out, int Nout) {
    __shared__ alignas(16) char smem[3 * 16384];  // 48 KB

    const int tid = threadIdx.x;
    const int bid = blockIdx.x;
    // XCD-bijective: xcd = bid&7 owns m-panels {4x..4x+3}.
    const int m0 = ((bid & 7) * 4 + ((bid >> 3) & 3)) * 64;
    const int n0 = (bid >> 5) * 64;

    const char* gsP[2]; int ldP[2];
#pragma unroll
    for (int i = 0; i < 2; ++i) {
        const int G = tid + 256 * i;
        gsP[i] = (const char*)P + (size_t)(m0 + (G >> 3)) * ROWB + (G & 7) * 16;
        ldP[i] = G * 16;
    }
    const char* gsQ[2]; int ldQ[2];
#pragma unroll
    for (int c = 0; c < 2; ++c) {
        const int g = tid + 256 * c;
        gsQ[c] = (const char*)Q + (size_t)(n0 + (g >> 3)) * ROWB + (g & 7) * 16;
        ldQ[c] = 8192 + g * 16;
    }

    const int lane = tid & 63;
    const int w = tid >> 6;           // 4 waves: 2m x 2n, wave tile 32x32
    const int wm = (w & 1) * 32;
    const int wn = (w >> 1) * 32;
    const int l15 = lane & 15, l4 = lane >> 4;
    const int off0 = (l4 * 16) ^ ((lane & 7) << 4);
    const int off1 = off0 ^ 64;

    f32x4 acc[2][2] = {};

    auto stage = [&](int s) {
        const int go = s * 128;
        char* base = smem + (s % 3) * 16384;
#pragma unroll
        for (int i = 0; i < 2; ++i) gload16(gsP[i] + go, base + ldP[i]);
#pragma unroll
        for (int c = 0; c < 2; ++c) gload16(gsQ[c] + go, base + ldQ[c]);
    };

    stage(0);
    stage(1);

    for (int s = 0; s < 16; ++s) {
        if (s == 15) asm volatile("s_waitcnt vmcnt(0)" ::: "memory");
        else         asm volatile("s_waitcnt vmcnt(4)" ::: "memory");
        __builtin_amdgcn_s_barrier();
        asm volatile("" ::: "memory");
        if (s < 14) stage(s + 2);
        const char* PtB = smem + (s % 3) * 16384;
        const char* QtB = PtB + 8192;
        __builtin_amdgcn_s_setprio(1);
#pragma unroll
        for (int h = 0; h < 2; ++h) {
            const int ko = h ? off1 : off0;
            f16x8 qa[2], pb[2];
#pragma unroll
            for (int i = 0; i < 2; ++i)
                qa[i] = *(const f16x8*)(QtB + (wn + i * 16 + l15) * 128 + ko);
#pragma unroll
            for (int j = 0; j < 2; ++j)
                pb[j] = *(const f16x8*)(PtB + (wm + j * 16 + l15) * 128 + ko);
#pragma unroll
            for (int i = 0; i < 2; ++i)
#pragma unroll
                for (int j = 0; j < 2; ++j)
                    acc[i][j] = __builtin_amdgcn_mfma_f32_16x16x32_f16(qa[i], pb[j], acc[i][j], 0, 0, 0);
        }
        __builtin_amdgcn_s_setprio(0);
    }

#pragma unroll
    for (int j = 0; j < 2; ++j) {
        const int m = m0 + wm + j * 16 + l15;
        float msk = 1.0f;
        if (EPI == 1) msk = (msum_in[m] * (1.0f / 1024.0f) > EPS_GATE) ? 1.0f : 0.0f;
        float rsum = 0.0f;
#pragma unroll
        for (int i = 0; i < 2; ++i) {
            const int n = n0 + wn + i * 16 + l4 * 4;
            const f32x4 bz = *(const f32x4*)(bias + n);
            float v[4];
#pragma unroll
            for (int e = 0; e < 4; ++e) {
                v[e] = acc[i][j][e] + bz[e];
                if (EPI == 1) v[e] = msk * (0.5f * tanh_fast(v[e]));
                if (EMIT) rsum += fabsf(v[e]);
            }
            if (EPI == 2) {
                f32x4 o; o[0] = v[0]; o[1] = v[1]; o[2] = v[2]; o[3] = v[3];
                *(f32x4*)((float*)Out + (size_t)m * Nout + n) = o;
            } else {
                f16x4 hv;
                hv[0] = (half_t)v[0]; hv[1] = (half_t)v[1];
                hv[2] = (half_t)v[2]; hv[3] = (half_t)v[3];
                const int p = (n * 2) ^ ((m & 7) << 4);
                *(f16x4*)((char*)Out + (size_t)m * ROWB + p) = hv;
            }
        }
        if (EMIT) {
            rsum += __shfl_xor(rsum, 16, 64);
            rsum += __shfl_xor(rsum, 32, 64);
            if (l4 == 0) atomicAdd(msum_out + m, rsum);
        }
    }
}

extern "C" void kernel_launch(void* const* d_in, const int* in_sizes, int n_in,
                              void* d_out, int out_size, void* d_ws, size_t ws_size,
                              hipStream_t stream) {
    const float* x  = (const float*)d_in[0];  // [2048,1024]
    const float* We = (const float*)d_in[1];  // [1024,1024]
    const float* be = (const float*)d_in[2];  // [1024]
    const float* W  = (const float*)d_in[3];  // [3,1024,1024]
    const float* b  = (const float*)d_in[4];  // [3,1024]
    const float* Wh = (const float*)d_in[5];  // [512,1024]
    const float* bh = (const float*)d_in[6];  // [512]

    const int B = 2048, H = 1024, O = 512;

    half_t* s0   = (half_t*)d_ws;                   // x16 / H0 / H2
    half_t* s1   = s0 + (size_t)B * H;              // E / H1
    half_t* We16 = s1 + (size_t)B * H;
    half_t* W16  = We16 + (size_t)H * H;
    half_t* Wh16 = W16 + (size_t)3 * H * H;
    float*  msum = (float*)(Wh16 + (size_t)O * H);  // 3 x 2048 f32
    float*  out  = (float*)d_out;

    convert_all<<<6656, 256, 0, stream>>>(x, We, W, Wh, s0, We16, W16, Wh16, msum);

    // E = x @ We^T + be; emit |E| row sums -> msum0
    gemm8w<0, true ><<<256, 512, 0, stream>>>(s0, We16, be, nullptr, msum, s1, H);
    // H0 = m0 * 0.5*tanh(E @ W0^T + b0); emit -> msum1
    gemm8w<1, true ><<<256, 512, 0, stream>>>(s1, W16, b, msum, msum + 2048, s0, H);
    // H1; emit -> msum2
    gemm8w<1, true ><<<256, 512, 0, stream>>>(s0, W16 + (size_t)H * H, b + H,
                                              msum + 2048, msum + 4096, s1, H);
    // H2 (no emit)
    gemm8w<1, false><<<256, 512, 0, stream>>>(s1, W16 + (size_t)2 * H * H, b + 2 * H,
                                              msum + 4096, nullptr, s0, H);
    // head -> f32 out: 64x64 tiles, 256 blocks (all CUs)
    gemm2b<2, false><<<256, 256, 0, stream>>>(s0, Wh16, bh, nullptr, nullptr, out, O);
}